// Round 5
// baseline (1017.348 us; speedup 1.0000x reference)
//
#include <hip/hip_runtime.h>

// ResNetBlock_MoE: B=64,C=64,H=W=56,E=8,TOPK=2. Inputs f32, outputs f32
// (confirmed R4: dtype self-detect took the f32 branch; output buffer is the
// reference's f32). out = sum_k w_k*relu(bn2(conv2(relu(bn1(conv1(x,e)))))+x),
// plus dense_w [B,E] appended flat in d_out.
//
// Fully fused: one block per (image, 8x8 tile); conv1 h kept in LDS (10x10
// halo), conv2 + residual + top-2 combine in registers. bf16 MFMA internally
// (threshold 0.1325 licenses it); residual added in exact f32.
// Zero d_ws usage (R1/R2 aborts correlated with any ws use).

#define BATCH 64
#define CH    64
#define HW_   3136            // 56*56
#define IMG_  (CH*HW_)        // 200704
#define NE    8
#define WSLICE 36864          // per-expert weights: 64*64*9

typedef unsigned short u16;
typedef __attribute__((ext_vector_type(8))) short short8_t;  // 8 bf16 = 4 VGPR
typedef __attribute__((ext_vector_type(4))) float floatx4;

__device__ __forceinline__ float b2f(unsigned u) {
    unsigned v = (u & 0xFFFFu) << 16;
    float f; __builtin_memcpy(&f, &v, 4); return f;
}
__device__ __forceinline__ u16 f2b(float f) {
    unsigned v; __builtin_memcpy(&v, &f, 4);
    return (u16)((v + 0x7FFFu + ((v >> 16) & 1u)) >> 16);   // RNE
}

// ---------------- gating: GAP -> linear -> top2 softmax -> dense_w (f32) ----
__global__ __launch_bounds__(256) void gate_kernel(
    const float* __restrict__ x, const float* __restrict__ gw,
    const float* __restrict__ gb, float* __restrict__ dw_out)
{
    __shared__ float part[256];
    __shared__ float pooled[CH];
    __shared__ float logits[NE];
    int b = blockIdx.x, tid = threadIdx.x;
    int c = tid >> 2, p = tid & 3;
    const float4* src = (const float4*)(x + (size_t)b*IMG_ + c*HW_ + p*784);
    float s = 0.f;
    for (int i = 0; i < 196; i++) {
        float4 u = src[i];
        s += u.x + u.y + u.z + u.w;
    }
    part[tid] = s;
    __syncthreads();
    if (tid < CH)
        pooled[tid] = (part[4*tid] + part[4*tid+1] + part[4*tid+2] + part[4*tid+3]) * (1.f/3136.f);
    __syncthreads();
    if (tid < NE) {
        float l = gb[tid];
        for (int cc = 0; cc < CH; cc++) l += pooled[cc] * gw[tid*CH + cc];
        logits[tid] = l;
    }
    __syncthreads();
    if (tid == 0) {
        int i1 = 0; float v1 = logits[0];
        for (int e = 1; e < NE; e++) if (logits[e] > v1) { v1 = logits[e]; i1 = e; }
        int i2 = -1; float v2 = -3.4e38f;
        for (int e = 0; e < NE; e++) if (e != i1 && logits[e] > v2) { v2 = logits[e]; i2 = e; }
        float eb = __expf(v2 - v1);
        float wa = 1.f / (1.f + eb), wb = eb / (1.f + eb);
        for (int e = 0; e < NE; e++) dw_out[b*NE + e] = 0.f;
        dw_out[b*NE + i1] = wa;
        dw_out[b*NE + i2] = wb;
    }
}

// ---------------- fused MoE basic block, one (image, 8x8 tile) per block -----
// xL: [144 pos][72] ch-inner bf16 (12x12 x-halo); hL: [100 pos][72] (10x10).
// Stride 72 u16 = 144 B: 16B-aligned b128 reads, ~4-way banks.
__global__ __launch_bounds__(256) void fused_kernel(
    const float* __restrict__ x,
    const float* __restrict__ w1, const float* __restrict__ s1, const float* __restrict__ b1,
    const float* __restrict__ w2, const float* __restrict__ s2, const float* __restrict__ b2,
    const float* __restrict__ dw, float* __restrict__ out)
{
    __shared__ u16 xL[144*72];
    __shared__ u16 hL[100*72];
    __shared__ int   sE[2];
    __shared__ float sW[2];

    int b    = blockIdx.y;
    int tile = blockIdx.x;              // 0..48
    int ty0 = (tile / 7) * 8, tx0 = (tile % 7) * 8;
    int tid = threadIdx.x;
    int lane = tid & 63, wv = tid >> 6;
    int l15 = lane & 15, q = lane >> 4, qk = q * 8;
    int m = wv * 16 + l15;              // A-operand row for this lane

    if (tid == 0) {
        int e0 = -1, e1 = -1; float wv0 = 0.f, wv1 = 0.f;
        for (int e = 0; e < NE; e++) {
            float w = dw[b*NE + e];
            if (w != 0.f) { if (e0 < 0) { e0 = e; wv0 = w; } else { e1 = e; wv1 = w; } }
        }
        if (e0 < 0) { e0 = 0; wv0 = 0.f; }
        if (e1 < 0) { e1 = e0; wv1 = 0.f; }
        sE[0] = e0; sE[1] = e1; sW[0] = wv0; sW[1] = wv1;
    }

    // ---- stage x tile (zero-padded 12x12 halo, all 64 ch) into xL as bf16 ---
    const float* xb = x + (size_t)b * IMG_;
    #pragma unroll
    for (int i = 0; i < 36; i++) {
        int idx = tid + i * 256;        // 0..9215
        int ch  = idx / 144;
        int pos = idx - ch * 144;
        int ry = pos / 12, rx = pos - ry * 12;
        int gy = ty0 - 2 + ry, gx = tx0 - 2 + rx;
        u16 v = 0;
        if ((unsigned)gy < 56u && (unsigned)gx < 56u) v = f2b(xb[ch*HW_ + gy*56 + gx]);
        xL[pos*72 + ch] = v;
    }
    __syncthreads();

    // per-lane position indices (k-loop invariant)
    int pIdx1[7];
    #pragma unroll
    for (int f = 0; f < 7; f++) {
        int n = f*16 + l15;             // conv1 GEMM col (0..111; >=100 = pad)
        int hy = n / 10, hx = n - hy*10;
        pIdx1[f] = (hy + 1) * 12 + (hx + 1);
    }
    int pIdx2[4];
    #pragma unroll
    for (int f = 0; f < 4; f++) {
        int n = f*16 + l15;             // conv2 GEMM col (0..63)
        int ty = n >> 3, tx = n & 7;
        pIdx2[f] = (ty + 1) * 10 + (tx + 1);
    }

    // residual, exact f32 from global
    float xres[4][4], oacc[4][4];
    #pragma unroll
    for (int f = 0; f < 4; f++) {
        int n = f*16 + l15;
        int ty = n >> 3, tx = n & 7;
        #pragma unroll
        for (int r = 0; r < 4; r++) {
            int mm = wv*16 + q*4 + r;
            xres[f][r] = xb[mm*HW_ + (ty0 + ty)*56 + (tx0 + tx)];
            oacc[f][r] = 0.f;
        }
    }

    for (int k = 0; k < 2; k++) {
        int e = sE[k];
        float wk = sW[k];
        const float* we1 = w1 + (size_t)e * WSLICE;
        const float* we2 = w2 + (size_t)e * WSLICE;

        // ---- conv1: h = relu(s1*(W1 (*) x) + b1) over 10x10 region ----
        floatx4 acc1[7];
        #pragma unroll
        for (int f = 0; f < 7; f++) acc1[f] = (floatx4){0.f,0.f,0.f,0.f};
        for (int s = 0; s < 18; s++) {
            int tap = s >> 1;
            int dy = tap / 3 - 1, dxk = tap - (tap/3)*3 - 1;
            int cib = ((s & 1) << 5) + qk;
            const float* ap = we1 + m*576 + cib*9 + tap;
            union { u16 u[8]; short8_t v; } A;
            #pragma unroll
            for (int j = 0; j < 8; j++) A.u[j] = f2b(ap[j*9]);
            int doff = dy*12 + dxk;
            #pragma unroll
            for (int f = 0; f < 7; f++) {
                int p = pIdx1[f] + doff;
                p = p < 143 ? p : 143;   // clamp pad cols (n>=100) into range
                short8_t bf = *(const short8_t*)&xL[p*72 + cib];
                acc1[f] = __builtin_amdgcn_mfma_f32_16x16x32_bf16(A.v, bf, acc1[f], 0, 0, 0);
            }
        }
        __syncthreads();                 // prev expert's conv2 hL readers done
        {
            float s1v[4], b1v[4];
            #pragma unroll
            for (int r = 0; r < 4; r++) {
                int mm = wv*16 + q*4 + r;
                s1v[r] = s1[e*64 + mm];
                b1v[r] = b1[e*64 + mm];
            }
            #pragma unroll
            for (int f = 0; f < 7; f++) {
                int n = f*16 + l15;
                if (n < 100) {
                    int hy = n / 10, hx = n - hy*10;
                    int gy = ty0 - 1 + hy, gx = tx0 - 1 + hx;
                    bool ins = (unsigned)gy < 56u && (unsigned)gx < 56u;
                    #pragma unroll
                    for (int r = 0; r < 4; r++) {
                        int mm = wv*16 + q*4 + r;
                        float v = ins ? fmaxf(acc1[f][r]*s1v[r] + b1v[r], 0.f) : 0.f;
                        hL[n*72 + mm] = f2b(v);   // zero outside image = conv2 pad
                    }
                }
            }
        }
        __syncthreads();                 // hL complete before conv2 reads

        // ---- conv2 + bn2 + residual + relu + weighted combine ----
        floatx4 acc2[4];
        #pragma unroll
        for (int f = 0; f < 4; f++) acc2[f] = (floatx4){0.f,0.f,0.f,0.f};
        for (int s = 0; s < 18; s++) {
            int tap = s >> 1;
            int dy = tap / 3 - 1, dxk = tap - (tap/3)*3 - 1;
            int cib = ((s & 1) << 5) + qk;
            const float* ap = we2 + m*576 + cib*9 + tap;
            union { u16 u[8]; short8_t v; } A;
            #pragma unroll
            for (int j = 0; j < 8; j++) A.u[j] = f2b(ap[j*9]);
            int doff = dy*10 + dxk;
            #pragma unroll
            for (int f = 0; f < 4; f++) {
                int p = pIdx2[f] + doff;          // always in [0,99]
                short8_t bf = *(const short8_t*)&hL[p*72 + cib];
                acc2[f] = __builtin_amdgcn_mfma_f32_16x16x32_bf16(A.v, bf, acc2[f], 0, 0, 0);
            }
        }
        {
            float s2v[4], b2v[4];
            #pragma unroll
            for (int r = 0; r < 4; r++) {
                int mm = wv*16 + q*4 + r;
                s2v[r] = s2[e*64 + mm];
                b2v[r] = b2[e*64 + mm];
            }
            #pragma unroll
            for (int f = 0; f < 4; f++)
                #pragma unroll
                for (int r = 0; r < 4; r++) {
                    float yv = acc2[f][r]*s2v[r] + b2v[r];
                    oacc[f][r] += wk * fmaxf(yv + xres[f][r], 0.f);
                }
        }
    }

    float* ob = out + (size_t)b * IMG_;
    #pragma unroll
    for (int f = 0; f < 4; f++) {
        int n = f*16 + l15;
        int ty = n >> 3, tx = n & 7;
        #pragma unroll
        for (int r = 0; r < 4; r++) {
            int mm = wv*16 + q*4 + r;
            ob[mm*HW_ + (ty0 + ty)*56 + (tx0 + tx)] = oacc[f][r];
        }
    }
}

extern "C" void kernel_launch(void* const* d_in, const int* in_sizes, int n_in,
                              void* d_out, int out_size, void* d_ws, size_t ws_size,
                              hipStream_t stream) {
    const float* x   = (const float*)d_in[0];
    const float* gw  = (const float*)d_in[1];
    const float* gb  = (const float*)d_in[2];
    const float* w1  = (const float*)d_in[3];
    const float* s1  = (const float*)d_in[4];
    const float* b1  = (const float*)d_in[5];
    const float* w2  = (const float*)d_in[6];
    const float* s2  = (const float*)d_in[7];
    const float* b2  = (const float*)d_in[8];
    float* out = (float*)d_out;
    float* dw  = out + (size_t)BATCH * IMG_;   // dense_w region of d_out (f32)

    (void)d_ws; (void)ws_size;                 // zero workspace usage

    hipLaunchKernelGGL(gate_kernel, dim3(BATCH), dim3(256), 0, stream, x, gw, gb, dw);
    hipLaunchKernelGGL(fused_kernel, dim3(49, BATCH), dim3(256), 0, stream,
                       x, w1, s1, b1, w2, s2, b2, dw, out);
}